// Round 4
// baseline (343.181 us; speedup 1.0000x reference)
//
#include <hip/hip_runtime.h>

// DeepComplexRBF, single cooperative kernel, 6 phases.
//   dist_sq[i] = sum_j |y[j] - G[i,j]|^2 ; phi[i] = exp(-dist_sq/(2 s[i]))
//   y_new[o]   = sum_i W[o,i]*phi[i] + b[o]
// 576 MB of G/W streamed once -> HBM/L3-bound, floor ~60-90 us.
//
// Round-3 lesson: 1 task per wave => phase time = slowest wave (no slack).
// Fix: block-per-row tasks (512 thr reduce one 32KB row), 4 rows/block
// interleaved -> per-block time averages 32 row-slices of memory luck.
// Barrier: per-phase relaxed agent-scope counter (validated protocol:
// __syncthreads drains vmcnt before arrival; all cross-phase data moves
// through agent-scope relaxed atomics at the coherence point).

#define D0 1024
#define H  4096
#define NT 512
#define NWB 8      // waves per block
#define NBLK 1024  // fixed grid: 4 blocks/CU x 256 CUs

typedef unsigned long long u64;

__device__ __forceinline__ float wave_sum(float v) {
#pragma unroll
    for (int off = 32; off > 0; off >>= 1) v += __shfl_down(v, off, 64);
    return v;
}

__device__ __forceinline__ void coh_store(float* p, float v) {
    __hip_atomic_store(p, v, __ATOMIC_RELAXED, __HIP_MEMORY_SCOPE_AGENT);
}

// stage n floats (n even) from coherence-point global into LDS
__device__ __forceinline__ void stage_coh(float* dst, const float* src, int n) {
    u64* d = (u64*)dst;
    const u64* s = (const u64*)src;
    for (int j = threadIdx.x; j < n / 2; j += NT)
        d[j] = __hip_atomic_load(const_cast<u64*>(&s[j]), __ATOMIC_RELAXED,
                                 __HIP_MEMORY_SCOPE_AGENT);
    __syncthreads();
}

// stage read-only kernel input (plain, vectorized)
__device__ __forceinline__ void stage_plain(float* dst, const float* __restrict__ src, int n) {
    for (int j = threadIdx.x * 4; j < n; j += NT * 4)
        *(float4*)(dst + j) = *(const float4*)(src + j);
    __syncthreads();
}

// symmetric counter barrier; ctr[phase*16] on its own 64B line
__device__ __forceinline__ void gridbar(int* ctr, int phase) {
    __syncthreads();   // all waves done; vmcnt drained (stores visible at L3)
    if (threadIdx.x == 0) {
        int* c = ctr + phase * 16;
        __hip_atomic_fetch_add(c, 1, __ATOMIC_RELAXED, __HIP_MEMORY_SCOPE_AGENT);
        while (__hip_atomic_load(c, __ATOMIC_RELAXED, __HIP_MEMORY_SCOPE_AGENT) < NBLK)
            __builtin_amdgcn_s_sleep(16);
    }
    __syncthreads();
}

// block-per-row: dist_sq + exp. G is (2, ROWS, COLS); y staged in LDS.
template <int COLS, int ROWS>
__device__ __forceinline__ void phi_rows(
        const float* __restrict__ G, const float* __restrict__ sv,
        float* phi, const float* syr, const float* syi, float* sred) {
    const int tid = threadIdx.x, lane = tid & 63, w = tid >> 6;
#pragma unroll
    for (int k = 0; k < ROWS / NBLK; ++k) {
        const int row = blockIdx.x + k * NBLK;
        const float* gre = G + (size_t)row * COLS;
        const float* gim = gre + (size_t)ROWS * COLS;
        float acc = 0.f;
        if (COLS >= 2048) {
#pragma unroll
            for (int j = tid * 4; j < COLS; j += NT * 4) {
                float4 gr = *(const float4*)(gre + j);
                float4 gi = *(const float4*)(gim + j);
                float4 yr = *(const float4*)(syr + j);
                float4 yi = *(const float4*)(syi + j);
                float dr, di;
                dr = yr.x - gr.x; di = yi.x - gi.x; acc += dr * dr + di * di;
                dr = yr.y - gr.y; di = yi.y - gi.y; acc += dr * dr + di * di;
                dr = yr.z - gr.z; di = yi.z - gi.z; acc += dr * dr + di * di;
                dr = yr.w - gr.w; di = yi.w - gi.w; acc += dr * dr + di * di;
            }
        } else {  // COLS == 1024: one float2 per lane
            const int j = tid * 2;
            float2 gr = *(const float2*)(gre + j);
            float2 gi = *(const float2*)(gim + j);
            float2 yr = *(const float2*)(syr + j);
            float2 yi = *(const float2*)(syi + j);
            float dr, di;
            dr = yr.x - gr.x; di = yi.x - gi.x; acc += dr * dr + di * di;
            dr = yr.y - gr.y; di = yi.y - gi.y; acc += dr * dr + di * di;
        }
        acc = wave_sum(acc);
        if (lane == 0) sred[w] = acc;
        __syncthreads();
        if (tid == 0) {
            float d = 0.f;
#pragma unroll
            for (int q = 0; q < NWB; ++q) d += sred[q];
            coh_store(&phi[row], expf(-d / (2.0f * sv[row])));
        }
        __syncthreads();
    }
}

// block-per-row: y = W @ phi + b. W is (2, ROWS, COLS); phi staged in LDS.
template <int COLS, int ROWS, bool COH>
__device__ __forceinline__ void w_rows(
        const float* __restrict__ W, const float* __restrict__ b,
        const float* sphi, float* ore, float* oim, float* sred) {
    const int tid = threadIdx.x, lane = tid & 63, w = tid >> 6;
#pragma unroll
    for (int k = 0; k < ROWS / NBLK; ++k) {
        const int row = blockIdx.x + k * NBLK;
        const float* wre = W + (size_t)row * COLS;
        const float* wim = wre + (size_t)ROWS * COLS;
        float ar = 0.f, ai = 0.f;
#pragma unroll
        for (int j = tid * 4; j < COLS; j += NT * 4) {
            float4 r = *(const float4*)(wre + j);
            float4 i = *(const float4*)(wim + j);
            float4 p = *(const float4*)(sphi + j);
            ar += r.x * p.x + r.y * p.y + r.z * p.z + r.w * p.w;
            ai += i.x * p.x + i.y * p.y + i.z * p.z + i.w * p.w;
        }
        ar = wave_sum(ar);
        ai = wave_sum(ai);
        if (lane == 0) { sred[w] = ar; sred[NWB + w] = ai; }
        __syncthreads();
        if (tid == 0) {
            float vr = 0.f, vi = 0.f;
#pragma unroll
            for (int q = 0; q < NWB; ++q) { vr += sred[q]; vi += sred[NWB + q]; }
            vr += b[row];
            vi += b[ROWS + row];
            if (COH) { coh_store(&ore[row], vr); coh_store(&oim[row], vi); }
            else     { ore[row] = vr; oim[row] = vi; }
        }
        __syncthreads();
    }
}

__global__ __launch_bounds__(NT, 8) void rbf_fused(
        const float* __restrict__ x,
        const float* __restrict__ W1, const float* __restrict__ b1,
        const float* __restrict__ G1, const float* __restrict__ s1,
        const float* __restrict__ W2, const float* __restrict__ b2,
        const float* __restrict__ G2, const float* __restrict__ s2,
        const float* __restrict__ W3, const float* __restrict__ b3,
        const float* __restrict__ G3, const float* __restrict__ s3,
        float* __restrict__ out, float* ws, int* ctr) {
    __shared__ float sm[2 * H + 16];   // 32.8 KB -> 4 blocks/CU
    float* sred = sm + 2 * H;
    float* phi = ws;          // 4096
    float* yre = ws + H;      // 4096
    float* yim = ws + 2 * H;  // 4096 (contiguous with yre)

    // ---- L1
    stage_plain(sm, x, 2 * D0);
    phi_rows<D0, H>(G1, s1, phi, sm, sm + D0, sred);
    gridbar(ctr, 0);

    stage_coh(sm, phi, H);
    w_rows<H, H, true>(W1, b1, sm, yre, yim, sred);
    gridbar(ctr, 1);

    // ---- L2
    stage_coh(sm, yre, 2 * H);
    phi_rows<H, H>(G2, s2, phi, sm, sm + H, sred);
    gridbar(ctr, 2);

    stage_coh(sm, phi, H);
    w_rows<H, H, true>(W2, b2, sm, yre, yim, sred);
    gridbar(ctr, 3);

    // ---- L3
    stage_coh(sm, yre, 2 * H);
    phi_rows<H, H>(G3, s3, phi, sm, sm + H, sred);
    gridbar(ctr, 4);

    stage_coh(sm, phi, H);
    w_rows<H, D0, false>(W3, b3, sm, out, out + D0, sred);
}

extern "C" void kernel_launch(void* const* d_in, const int* in_sizes, int n_in,
                              void* d_out, int out_size, void* d_ws, size_t ws_size,
                              hipStream_t stream) {
    const float* x  = (const float*)d_in[0];
    const float* W1 = (const float*)d_in[1];
    const float* b1 = (const float*)d_in[2];
    const float* G1 = (const float*)d_in[3];
    const float* s1 = (const float*)d_in[4];
    const float* W2 = (const float*)d_in[5];
    const float* b2 = (const float*)d_in[6];
    const float* G2 = (const float*)d_in[7];
    const float* s2 = (const float*)d_in[8];
    const float* W3 = (const float*)d_in[9];
    const float* b3 = (const float*)d_in[10];
    const float* G3 = (const float*)d_in[11];
    const float* s3 = (const float*)d_in[12];
    float* out = (float*)d_out;   // (2, 1024)
    float* ws  = (float*)d_ws;    // phi[H], yre[H], yim[H], then barrier ints
    int* ctr = (int*)(ws + 3 * H);

    // re-zero barrier counters on every (graph-replayed) call
    hipMemsetAsync(ctr, 0, 1024 * sizeof(int), stream);

    void* args[] = {&x, &W1, &b1, &G1, &s1, &W2, &b2, &G2, &s2,
                    &W3, &b3, &G3, &s3, &out, &ws, &ctr};
    hipLaunchCooperativeKernel((const void*)rbf_fused, dim3(NBLK), dim3(NT),
                               args, 0, stream);
}

// Round 5
// 151.865 us; speedup vs baseline: 2.2598x; 2.2598x over previous
//
#include <hip/hip_runtime.h>

// DeepComplexRBF, single cooperative kernel, 6 phases + epilogue.
//   dist_sq[i] = sum_j |y[j] - G[i,j]|^2 ; phi[i] = exp(-dist_sq/(2 s[i]))
//   y_new[o]   = sum_i W[o,i]*phi[i] + b[o]
// 576 MB of G/W streamed once (plain cached float4 loads, coalesced).
//
// Round-3/4 lesson: the hidden cost was ALL blocks re-reading the same
// 16-32 KB shared vector via 8B agent-scope atomic loads (hot-line
// serialization at the coherence point), plus lockstep syncs (r4).
// This version:
//  - column strips: block stages only its 4KB strip slice
//  - partials stored race-free to arr[row*4+strip] (relaxed agent stores,
//    unique addresses, deterministic); consumer sums 4 partials in staging
//  - 256 blocks x 1024 thr (1/CU): 4x fewer stagings, waves run free
//  - slot barrier on distinct 64B lines (validated protocol: __syncthreads
//    drains vmcnt before the arrival store)

#define D0 1024
#define H  4096
#define NT 1024
#define NBLK 256

typedef unsigned long long u64;

__device__ __forceinline__ float wave_sum(float v) {
#pragma unroll
    for (int off = 32; off > 0; off >>= 1) v += __shfl_down(v, off, 64);
    return v;
}

__device__ __forceinline__ u64 cld64(const float* p) {
    return __hip_atomic_load((u64*)p, __ATOMIC_RELAXED, __HIP_MEMORY_SCOPE_AGENT);
}
__device__ __forceinline__ void cst(float* p, float v) {
    __hip_atomic_store(p, v, __ATOMIC_RELAXED, __HIP_MEMORY_SCOPE_AGENT);
}
__device__ __forceinline__ int cldi(const int* p) {
    return __hip_atomic_load((int*)p, __ATOMIC_RELAXED, __HIP_MEMORY_SCOPE_AGENT);
}
__device__ __forceinline__ void csti(int* p, int v) {
    __hip_atomic_store(p, v, __ATOMIC_RELAXED, __HIP_MEMORY_SCOPE_AGENT);
}
__device__ __forceinline__ float2 f2(u64 v) {
    float2 f; __builtin_memcpy(&f, &v, 8); return f;
}

// slot barrier: distinct 64B lines, block0 polls in parallel then sets gen.
__device__ __forceinline__ void gridbar(int* slots, int* gen, int phase) {
    __syncthreads();   // all waves done; vmcnt drained -> partial stores visible
    const int t = threadIdx.x;
    if (blockIdx.x == 0) {
        if (t >= 1 && t < NBLK)
            while (cldi(slots + t * 16) < phase) __builtin_amdgcn_s_sleep(8);
        __syncthreads();
        if (t == 0) csti(gen, phase);
    } else {
        if (t == 0) {
            csti(slots + blockIdx.x * 16, phase);
            while (cldi(gen) < phase) __builtin_amdgcn_s_sleep(8);
        }
        __syncthreads();
    }
}

// ---- staging (per-block, into LDS) ----
__device__ __forceinline__ void stage_x(float* sm, const float* __restrict__ x) {
    const int t = threadIdx.x;
    if (t < 512) *(float4*)(sm + 4 * t) = *(const float4*)(x + 4 * t);
    __syncthreads();
}
// phi strip: sum 4 dist^2 partials, apply exp
__device__ __forceinline__ void stage_phi(const float* dsq4, const float* __restrict__ sv,
                                          int so, float* sphi) {
    const int i = so + threadIdx.x;
    float2 a = f2(cld64(dsq4 + i * 4));
    float2 b = f2(cld64(dsq4 + i * 4 + 2));
    const float d = (a.x + a.y) + (b.x + b.y);
    sphi[threadIdx.x] = expf(-d / (2.0f * sv[i]));
    __syncthreads();
}
// y strip: sum 4 matmul partials, add bias (re & im)
__device__ __forceinline__ void stage_y(const float* yre4, const float* yim4,
                                        const float* __restrict__ bias, int PR,
                                        int so, float* syr, float* syi) {
    const int t = threadIdx.x;
    const int o = so + t;
    float2 a = f2(cld64(yre4 + o * 4));
    float2 b = f2(cld64(yre4 + o * 4 + 2));
    syr[t] = (a.x + a.y) + (b.x + b.y) + bias[o];
    float2 c = f2(cld64(yim4 + o * 4));
    float2 d = f2(cld64(yim4 + o * 4 + 2));
    syi[t] = (c.x + c.y) + (d.x + d.y) + bias[PR + o];
    __syncthreads();
}

// ---- streaming workers: wave-per-(row,strip) task, no intra-phase syncs ----
template <int COLS, int ROWS, int KMAX, int RSTRIDE>
__device__ __forceinline__ void phi_strip(
        const float* __restrict__ G, float* dsq4,
        const float* syr, const float* syi,
        int so, int strip, int rbase, int w, int lane) {
#pragma unroll
    for (int k = 0; k < KMAX; ++k) {
        const int row = rbase + RSTRIDE * (w + 16 * k);
        const float* gre = G + (size_t)row * COLS + so;
        const float* gim = gre + (size_t)ROWS * COLS;
        float acc = 0.f;
#pragma unroll
        for (int it = 0; it < 4; ++it) {
            const int j = lane * 4 + it * 256;
            float4 gr = *(const float4*)(gre + j);
            float4 gi = *(const float4*)(gim + j);
            float4 yr = *(const float4*)(syr + j);
            float4 yi = *(const float4*)(syi + j);
            float dr, di;
            dr = yr.x - gr.x; di = yi.x - gi.x; acc += dr * dr + di * di;
            dr = yr.y - gr.y; di = yi.y - gi.y; acc += dr * dr + di * di;
            dr = yr.z - gr.z; di = yi.z - gi.z; acc += dr * dr + di * di;
            dr = yr.w - gr.w; di = yi.w - gi.w; acc += dr * dr + di * di;
        }
        acc = wave_sum(acc);
        if (lane == 0) cst(&dsq4[row * 4 + strip], acc);
    }
}

template <int COLS, int ROWS, int KMAX, int RSTRIDE>
__device__ __forceinline__ void w_strip(
        const float* __restrict__ W, float* re4, float* im4,
        const float* sphi, int so, int strip, int rbase, int w, int lane) {
#pragma unroll
    for (int k = 0; k < KMAX; ++k) {
        const int row = rbase + RSTRIDE * (w + 16 * k);
        const float* wre = W + (size_t)row * COLS + so;
        const float* wim = wre + (size_t)ROWS * COLS;
        float ar = 0.f, ai = 0.f;
#pragma unroll
        for (int it = 0; it < 4; ++it) {
            const int j = lane * 4 + it * 256;
            float4 r = *(const float4*)(wre + j);
            float4 i = *(const float4*)(wim + j);
            float4 p = *(const float4*)(sphi + j);
            ar += r.x * p.x + r.y * p.y + r.z * p.z + r.w * p.w;
            ai += i.x * p.x + i.y * p.y + i.z * p.z + i.w * p.w;
        }
        ar = wave_sum(ar);
        ai = wave_sum(ai);
        if (lane == 0) {
            cst(&re4[row * 4 + strip], ar);
            cst(&im4[row * 4 + strip], ai);
        }
    }
}

__global__ __launch_bounds__(NT, 4) void rbf_fused(
        const float* __restrict__ x,
        const float* __restrict__ W1, const float* __restrict__ b1,
        const float* __restrict__ G1, const float* __restrict__ s1,
        const float* __restrict__ W2, const float* __restrict__ b2,
        const float* __restrict__ G2, const float* __restrict__ s2,
        const float* __restrict__ W3, const float* __restrict__ b3,
        const float* __restrict__ G3, const float* __restrict__ s3,
        float* __restrict__ out, float* ws, int* bar) {
    __shared__ float sm[2048];
    float* dsqA = ws;              // 16384: dsq1 partials, reused for dsq3
    float* dsqB = ws + 16384;      // 16384: dsq2 partials
    float* yre4 = ws + 32768;      // 16384: y partials re (L1 then L2)
    float* yim4 = ws + 49152;      // 16384: y partials im
    float* oac4 = ws + 65536;      // 8192:  out partials [re rows | im rows]
    int* slots = bar;
    int* gen = bar + NBLK * 16;

    const int lane = threadIdx.x & 63, w = threadIdx.x >> 6;
    const int strip = blockIdx.x & 3, g = blockIdx.x >> 2;  // 4 strips x 64 groups
    const int so = strip * 1024;

    // P1: dsq1 (G1 (2,H,D0)); whole-row tasks (one partial; other 3 slots are
    // zero from the launch memset). rows = blockIdx + 256*w.
    stage_x(sm, x);
    phi_strip<D0, H, 1, 256>(G1, dsqA, sm, sm + 1024, 0, strip, blockIdx.x, w, lane);
    gridbar(slots, gen, 1);

    // P2: y1 = W1 @ phi1 (W1 (2,H,H))
    stage_phi(dsqA, s1, so, sm);
    w_strip<H, H, 4, 64>(W1, yre4, yim4, sm, so, strip, g, w, lane);
    gridbar(slots, gen, 2);

    // P3: dsq2 (G2 (2,H,H)); stage y1 + b1
    stage_y(yre4, yim4, b1, H, so, sm, sm + 1024);
    phi_strip<H, H, 4, 64>(G2, dsqB, sm, sm + 1024, so, strip, g, w, lane);
    gridbar(slots, gen, 3);

    // P4: y2 = W2 @ phi2 (reuse y partial buffers; fully overwritten)
    stage_phi(dsqB, s2, so, sm);
    w_strip<H, H, 4, 64>(W2, yre4, yim4, sm, so, strip, g, w, lane);
    gridbar(slots, gen, 4);

    // P5: dsq3 (G3); reuse dsqA (fully overwritten: all 4 strips write)
    stage_y(yre4, yim4, b2, H, so, sm, sm + 1024);
    phi_strip<H, H, 4, 64>(G3, dsqA, sm, sm + 1024, so, strip, g, w, lane);
    gridbar(slots, gen, 5);

    // P6: out partials = W3 @ phi3 (W3 (2,D0,H)); rows 0..1023 = g + 64*w
    stage_phi(dsqA, s3, so, sm);
    w_strip<H, D0, 1, 64>(W3, oac4, oac4 + 4096, sm, so, strip, g, w, lane);

    // final arrive; block 0 waits and does the epilogue out = sum4 + b3
    __syncthreads();
    if (blockIdx.x == 0) {
        const int t = threadIdx.x;
        if (t >= 1 && t < NBLK)
            while (cldi(slots + t * 16) < 6) __builtin_amdgcn_s_sleep(8);
        __syncthreads();
#pragma unroll
        for (int r = 0; r < 2; ++r) {
            const int o = t + r * 1024;   // 0..2047 covers (2,1024) out
            float2 a = f2(cld64(oac4 + o * 4));
            float2 b = f2(cld64(oac4 + o * 4 + 2));
            out[o] = (a.x + a.y) + (b.x + b.y) + b3[o];
        }
    } else {
        if (threadIdx.x == 0) csti(slots + blockIdx.x * 16, 6);
    }
}

extern "C" void kernel_launch(void* const* d_in, const int* in_sizes, int n_in,
                              void* d_out, int out_size, void* d_ws, size_t ws_size,
                              hipStream_t stream) {
    const float* x  = (const float*)d_in[0];
    const float* W1 = (const float*)d_in[1];
    const float* b1 = (const float*)d_in[2];
    const float* G1 = (const float*)d_in[3];
    const float* s1 = (const float*)d_in[4];
    const float* W2 = (const float*)d_in[5];
    const float* b2 = (const float*)d_in[6];
    const float* G2 = (const float*)d_in[7];
    const float* s2 = (const float*)d_in[8];
    const float* W3 = (const float*)d_in[9];
    const float* b3 = (const float*)d_in[10];
    const float* G3 = (const float*)d_in[11];
    const float* s3 = (const float*)d_in[12];
    float* out = (float*)d_out;   // (2, 1024)
    float* ws  = (float*)d_ws;
    int* bar = (int*)(ws + 73728);

    // zero partial buffers + barrier state every (graph-replayed) call:
    // 73728 floats of partials + 256*16+16 ints of barrier = ~305 KB
    hipMemsetAsync(ws, 0, 73728 * sizeof(float) + (NBLK * 16 + 16) * sizeof(int),
                   stream);

    void* args[] = {&x, &W1, &b1, &G1, &s1, &W2, &b2, &G2, &s2,
                    &W3, &b3, &G3, &s3, &out, &ws, &bar};
    hipLaunchCooperativeKernel((const void*)rbf_fused, dim3(NBLK), dim3(NT),
                               args, 0, stream);
}

// Round 6
// 119.300 us; speedup vs baseline: 2.8766x; 1.2730x over previous
//
#include <hip/hip_runtime.h>

// DeepComplexRBF as 6 plain kernels in the captured graph (one per phase).
//   dist_sq[i] = sum_j |y[j] - G[i,j]|^2 ; phi[i] = exp(-dist_sq/(2 s[i]))
//   y_new[o]   = sum_i W[o,i]*phi[i] + b[o]
// 576 MB of G/W streamed once -> memory-bound, floor ~90 us + graph gaps.
//
// Lessons from rounds 2-5 (fused cooperative attempts, best 152 us):
// grid-wide barriers + agent-scope coherent traffic carried a ~70 us
// overhead my models repeatedly failed to attribute. Kernel boundaries
// provide ordering + cross-XCD coherence for free (HSA acquire/release),
// and rocprof reports per-phase timing. Round-1's naive version of this
// structure already did 137.7 us.
//
// Per-kernel design: wave-per-row, grid exactly = rows/4 (all resident),
// explicit 16-float4 load bursts for deep MLP (round 5's VGPR=36 schedule
// kept only ~2 loads in flight), shared vectors (y: 32 KB, phi: 16 KB)
// read per-lane through L1/L2 (no LDS, no staging redundancy).

#define D0 1024
#define H  4096

__device__ __forceinline__ float wave_sum(float v) {
#pragma unroll
    for (int off = 32; off > 0; off >>= 1) v += __shfl_down(v, off, 64);
    return v;
}

// One wave per row: phi[row] = exp(-|y - G[row]|^2 / (2 s[row])).
// G is (2, ROWS, COLS); y given as separate re/im pointers (COLS each).
template <int COLS, int ROWS>
__global__ __launch_bounds__(256) void phi_k(
        const float* __restrict__ G,
        const float* __restrict__ yre, const float* __restrict__ yim,
        const float* __restrict__ sv, float* __restrict__ phi) {
    const int lane = threadIdx.x & 63;
    const int row = (blockIdx.x * 256 + threadIdx.x) >> 6;
    const float* gre = G + (size_t)row * COLS;
    const float* gim = gre + (size_t)ROWS * COLS;

    constexpr int NIT = COLS / 256;  // float4 steps per lane (4 or 16)
    float acc = 0.f;
#pragma unroll
    for (int it0 = 0; it0 < NIT; it0 += 4) {
        float4 gr[4], gi[4], yr[4], yi[4];
#pragma unroll
        for (int u = 0; u < 4; ++u) {
            const int j = lane * 4 + (it0 + u) * 256;
            gr[u] = *(const float4*)(gre + j);
            gi[u] = *(const float4*)(gim + j);
            yr[u] = *(const float4*)(yre + j);
            yi[u] = *(const float4*)(yim + j);
        }
#pragma unroll
        for (int u = 0; u < 4; ++u) {
            float dr, di;
            dr = yr[u].x - gr[u].x; di = yi[u].x - gi[u].x; acc += dr * dr + di * di;
            dr = yr[u].y - gr[u].y; di = yi[u].y - gi[u].y; acc += dr * dr + di * di;
            dr = yr[u].z - gr[u].z; di = yi[u].z - gi[u].z; acc += dr * dr + di * di;
            dr = yr[u].w - gr[u].w; di = yi[u].w - gi[u].w; acc += dr * dr + di * di;
        }
    }
    acc = wave_sum(acc);
    if (lane == 0) phi[row] = expf(-acc / (2.0f * sv[row]));
}

// One wave per row: (ore,oim)[row] = W[row] . phi + b[row].
// W is (2, ROWS, COLS); bias is (2, ROWS) flat.
template <int COLS, int ROWS>
__global__ __launch_bounds__(256) void w_k(
        const float* __restrict__ W, const float* __restrict__ bias,
        const float* __restrict__ phi,
        float* __restrict__ ore, float* __restrict__ oim) {
    const int lane = threadIdx.x & 63;
    const int row = (blockIdx.x * 256 + threadIdx.x) >> 6;
    const float* wre = W + (size_t)row * COLS;
    const float* wim = wre + (size_t)ROWS * COLS;

    constexpr int NIT = COLS / 256;  // 16
    float ar = 0.f, ai = 0.f;
#pragma unroll
    for (int it0 = 0; it0 < NIT; it0 += 4) {
        float4 wr[4], wi[4], p[4];
#pragma unroll
        for (int u = 0; u < 4; ++u) {
            const int j = lane * 4 + (it0 + u) * 256;
            wr[u] = *(const float4*)(wre + j);
            wi[u] = *(const float4*)(wim + j);
            p[u]  = *(const float4*)(phi + j);
        }
#pragma unroll
        for (int u = 0; u < 4; ++u) {
            ar += wr[u].x * p[u].x + wr[u].y * p[u].y
                + wr[u].z * p[u].z + wr[u].w * p[u].w;
            ai += wi[u].x * p[u].x + wi[u].y * p[u].y
                + wi[u].z * p[u].z + wi[u].w * p[u].w;
        }
    }
    ar = wave_sum(ar);
    ai = wave_sum(ai);
    if (lane == 0) {
        ore[row] = ar + bias[row];
        oim[row] = ai + bias[ROWS + row];
    }
}

extern "C" void kernel_launch(void* const* d_in, const int* in_sizes, int n_in,
                              void* d_out, int out_size, void* d_ws, size_t ws_size,
                              hipStream_t stream) {
    const float* x  = (const float*)d_in[0];
    const float* W1 = (const float*)d_in[1];
    const float* b1 = (const float*)d_in[2];
    const float* G1 = (const float*)d_in[3];
    const float* s1 = (const float*)d_in[4];
    const float* W2 = (const float*)d_in[5];
    const float* b2 = (const float*)d_in[6];
    const float* G2 = (const float*)d_in[7];
    const float* s2 = (const float*)d_in[8];
    const float* W3 = (const float*)d_in[9];
    const float* b3 = (const float*)d_in[10];
    const float* G3 = (const float*)d_in[11];
    const float* s3 = (const float*)d_in[12];
    float* out = (float*)d_out;   // (2, 1024)

    float* ws  = (float*)d_ws;
    float* phi = ws;              // 4096
    float* yre = ws + H;          // 4096
    float* yim = ws + 2 * H;      // 4096
    // no init needed: phi/y fully written before first read each call

    // Layer 1
    phi_k<D0, H><<<H / 4, 256, 0, stream>>>(G1, x, x + D0, s1, phi);
    w_k<H, H><<<H / 4, 256, 0, stream>>>(W1, b1, phi, yre, yim);
    // Layer 2
    phi_k<H, H><<<H / 4, 256, 0, stream>>>(G2, yre, yim, s2, phi);
    w_k<H, H><<<H / 4, 256, 0, stream>>>(W2, b2, phi, yre, yim);
    // Layer 3
    phi_k<H, H><<<H / 4, 256, 0, stream>>>(G3, yre, yim, s3, phi);
    w_k<H, D0><<<D0 / 4, 256, 0, stream>>>(W3, b3, phi, out, out + D0);
}